// Round 2
// baseline (2741.436 us; speedup 1.0000x reference)
//
#include <hip/hip_runtime.h>
#include <hip/hip_bf16.h>
#include <hip/hip_cooperative_groups.h>

namespace cg = cooperative_groups;

constexpr int B = 512;
constexpr int I = 512;
constexpr int H = 1024;
constexpr int O = 512;

using short8 = __attribute__((ext_vector_type(8))) short;
using f32x4  = __attribute__((ext_vector_type(4))) float;
using bf16_t = __hip_bfloat16;

__device__ __forceinline__ short8 ldfrag(const bf16_t* p) {
    return *reinterpret_cast<const short8*>(p);
}
__device__ __forceinline__ float sigmoid_f(float z) {
    return 1.0f / (1.0f + __expf(-z));
}

// ---- XCD-local, RMW-free group barrier (with device-scope fallback) ----
// Group = 64 WGs with the same (blockIdx % 8); under MI355X round-robin
// dispatch they all live on ONE XCD, so the XCD L2 is the coherence point
// (round-0 kernel's plain-L2 h exchange passing absmax is the evidence).
// Old scheme: 64 agent-scope (sc1 -> MALL) fetch_adds on ONE counter line per
// step + 512 pollers on the same page => serialized LLC RMWs ~12us/step idle.
// New scheme (no RMWs, no resets, monotonic flags):
//   post: plain sc0 store of (t+1) into this WG's own local flag slot
//         (write-through -> lands in the XCD L2), PLUS an sc0 sc1 store into a
//         device-scope slot (write-through -> LLC). Two fire-and-forget stores.
//   wait: wave 0 polls the 64 local flags in parallel (one lane per flag) with
//         L1-bypassing sc0 loads served by the local L2 (~200cy, no MALL).
//         Every 64th poll it checks the LLC copy -> if co-XCD dispatch ever
//         fails to hold, the barrier still progresses (numerics would then
//         fail loudly instead of hanging).
// h stores are drained to L2 by group_post's __syncthreads (implicit vmcnt 0)
// BEFORE the flag stores; consumers buffer_inv sc0 (L1-only) after detection.
__device__ __forceinline__ int load_sc0(const int* p) {
    int v;
    asm volatile("global_load_dword %0, %1, off sc0\n\t"
                 "s_waitcnt vmcnt(0)"
                 : "=v"(v) : "v"(p) : "memory");
    return v;
}
__device__ __forceinline__ int load_sc01(const int* p) {
    int v;
    asm volatile("global_load_dword %0, %1, off sc0 sc1\n\t"
                 "s_waitcnt vmcnt(0)"
                 : "=v"(v) : "v"(p) : "memory");
    return v;
}

// group flag region layout (per group, 256 ints): local flag i at [i*2],
// device-scope flag i at [128 + i*2]  (8B spacing, both inside existing 8KB).
__device__ __forceinline__ void group_wait(const int* grp, int target) {
    if (threadIdx.x < 64) {
        const int* lp = grp + threadIdx.x * 2;
        const int* dp = grp + 128 + threadIdx.x * 2;
        int it = 0;
        while (load_sc0(lp) < target) {
            ++it;
            if ((it & 63) == 0) {
                if (load_sc01(dp) >= target) break;   // device-scope fallback
            }
            __builtin_amdgcn_s_sleep(1);
        }
    }
    __syncthreads();
    asm volatile("buffer_inv sc0" ::: "memory");     // L1-only invalidate
}

__device__ __forceinline__ void group_post(int* grp, int lblk, int value) {
    __syncthreads();  // drains this WG's h stores to local L2 (vmcnt 0)
    if (threadIdx.x == 0) {
        int* lp = grp + lblk * 2;
        int* dp = grp + 128 + lblk * 2;
        asm volatile("global_store_dword %0, %1, off sc0"
                     :: "v"(lp), "v"(value) : "memory");
        asm volatile("global_store_dword %0, %1, off sc0 sc1"
                     :: "v"(dp), "v"(value) : "memory");
    }
}

// 512 WGs x 256 thr, 64KB LDS (Wjh+Wkh slices), 2 WGs/CU.
// WG(g): iblk = g&7 (64 batch rows, XCD-local group), lblk = g>>3 (16 gate cols).
// lblk<32 WGs additionally compute 16 out cols (Wo streamed from L2).
__global__ __launch_bounds__(256, 2)
void flipflop_rnn_kernel(const float* __restrict__ x,  const float* __restrict__ h0,
                         const float* __restrict__ Wjx, const float* __restrict__ bjx,
                         const float* __restrict__ Wjh, const float* __restrict__ bjh,
                         const float* __restrict__ Wkx, const float* __restrict__ bkx,
                         const float* __restrict__ Wkh, const float* __restrict__ bkh,
                         const float* __restrict__ Wo,  const float* __restrict__ bo,
                         const int* __restrict__ seqlen,
                         float* __restrict__ out,
                         bf16_t* __restrict__ wjh_bf, bf16_t* __restrict__ wkh_bf,
                         bf16_t* __restrict__ wo_bf,  bf16_t* __restrict__ wjx_bf,
                         bf16_t* __restrict__ wkx_bf, bf16_t* __restrict__ x_bf,
                         bf16_t* __restrict__ hbf0,   bf16_t* __restrict__ hbf1,
                         int* __restrict__ cnt)
{
    // [gate][kb 0..127][col 0..15][8 shorts] = 65536 B
    __shared__ short lds_w[32768];

    const int T    = seqlen[0];
    const int tid  = threadIdx.x;
    const int g    = blockIdx.x;
    const int nthr = gridDim.x * blockDim.x;
    const int gtid = g * blockDim.x + tid;

    // ---- cast weights & x to bf16; zero barrier flags ----
    for (int idx = gtid; idx < H * H; idx += nthr) wjh_bf[idx] = __float2bfloat16(Wjh[idx]);
    for (int idx = gtid; idx < H * H; idx += nthr) wkh_bf[idx] = __float2bfloat16(Wkh[idx]);
    for (int idx = gtid; idx < O * H; idx += nthr) wo_bf[idx]  = __float2bfloat16(Wo[idx]);
    for (int idx = gtid; idx < H * I; idx += nthr) wjx_bf[idx] = __float2bfloat16(Wjx[idx]);
    for (int idx = gtid; idx < H * I; idx += nthr) wkx_bf[idx] = __float2bfloat16(Wkx[idx]);
    for (int idx = gtid; idx < B * I; idx += nthr) x_bf[idx]   = __float2bfloat16(x[idx]);
    if (gtid < 8 * 256) cnt[gtid] = 0;   // 8 groups x (64 local + 64 device) flags

    // ---- geometry ----
    const int w     = tid >> 6;
    const int lane  = tid & 63;
    const int quad  = lane >> 4;
    const int lm    = lane & 15;
    const int iblk  = g & 7;            // XCD-local group id
    const int lblk  = g >> 3;           // 0..63
    const int rbase = iblk * 64 + w * 16;
    const int n0    = lblk * 16;        // gate cols
    const bool has_out = (lblk < 32);
    const int no0   = lblk * 16;        // out cols (valid when has_out)
    int* grp_flags = cnt + iblk * 256;  // this group's flag region

    // ---- h0 init: each thread owns 4 (row,col) elements ----
    float hreg[4];
    #pragma unroll
    for (int r = 0; r < 4; ++r) {
        const int row = rbase + quad * 4 + r;
        const int col = n0 + lm;
        const float hv = h0[row * H + col];
        hreg[r] = hv;
        hbf0[row * H + col] = __float2bfloat16(hv);
    }

    cg::this_grid().sync();   // casts + h0 + flag zeros visible device-wide

    // ---- load this WG's Wjh/Wkh rows into LDS (one time) ----
    for (int c = tid; c < 4096; c += 256) {
        const int gate = c >> 11;
        const int cc   = c & 2047;
        const int kb   = cc >> 4;
        const int col  = cc & 15;
        const bf16_t* src = (gate ? wkh_bf : wjh_bf) + (n0 + col) * H + kb * 8;
        *reinterpret_cast<short8*>(&lds_w[c * 8]) = *reinterpret_cast<const short8*>(src);
    }
    __syncthreads();

    // ---- jx/kx (+ all biases) in registers ----
    float jxr[4], kxr[4];
    {
        f32x4 aJ = {0.f, 0.f, 0.f, 0.f};
        f32x4 aK = {0.f, 0.f, 0.f, 0.f};
        const bf16_t* aP = x_bf   + (rbase + lm) * I + quad * 8;
        const bf16_t* jP = wjx_bf + (n0 + lm) * I + quad * 8;
        const bf16_t* kP = wkx_bf + (n0 + lm) * I + quad * 8;
        #pragma unroll 4
        for (int k0 = 0; k0 < I; k0 += 32) {
            short8 a = ldfrag(aP + k0);
            aJ = __builtin_amdgcn_mfma_f32_16x16x32_bf16(a, ldfrag(jP + k0), aJ, 0, 0, 0);
            aK = __builtin_amdgcn_mfma_f32_16x16x32_bf16(a, ldfrag(kP + k0), aK, 0, 0, 0);
        }
        const int col = n0 + lm;
        #pragma unroll
        for (int r = 0; r < 4; ++r) {
            jxr[r] = aJ[r] + bjx[col] + bjh[col];
            kxr[r] = aK[r] + bkx[col] + bkh[col];
        }
    }
    const float bo_v = has_out ? bo[no0 + lm] : 0.0f;

    // ---- recurrence: step t reads h_t, computes h_{t+1} and out_{t-1} ----
    for (int t = 0; t < T; ++t) {
        if (t > 0) group_wait(grp_flags, t);   // h_t published by all 64 group WGs
        const bf16_t* hb  = (t & 1) ? hbf1 : hbf0;
        bf16_t*       hbn = (t & 1) ? hbf0 : hbf1;

        f32x4 accJ = {0.f, 0.f, 0.f, 0.f};
        f32x4 accK = {0.f, 0.f, 0.f, 0.f};
        f32x4 accO = {0.f, 0.f, 0.f, 0.f};

        const bf16_t* aP = hb    + (rbase + lm) * H + quad * 8;
        const bf16_t* oP = wo_bf + (no0 + lm) * H + quad * 8;
        const short*  jL = lds_w + quad * 128 + lm * 8;          // [kb][col][8]
        const short*  kL = jL + 16384;

        if (has_out) {
            #pragma unroll 4
            for (int k0 = 0; k0 < H; k0 += 32) {
                short8 a  = ldfrag(aP + k0);
                short8 bj = *reinterpret_cast<const short8*>(jL + (k0 >> 3) * 128);
                short8 bk = *reinterpret_cast<const short8*>(kL + (k0 >> 3) * 128);
                accJ = __builtin_amdgcn_mfma_f32_16x16x32_bf16(a, bj, accJ, 0, 0, 0);
                accK = __builtin_amdgcn_mfma_f32_16x16x32_bf16(a, bk, accK, 0, 0, 0);
                accO = __builtin_amdgcn_mfma_f32_16x16x32_bf16(a, ldfrag(oP + k0), accO, 0, 0, 0);
            }
        } else {
            #pragma unroll 4
            for (int k0 = 0; k0 < H; k0 += 32) {
                short8 a  = ldfrag(aP + k0);
                short8 bj = *reinterpret_cast<const short8*>(jL + (k0 >> 3) * 128);
                short8 bk = *reinterpret_cast<const short8*>(kL + (k0 >> 3) * 128);
                accJ = __builtin_amdgcn_mfma_f32_16x16x32_bf16(a, bj, accJ, 0, 0, 0);
                accK = __builtin_amdgcn_mfma_f32_16x16x32_bf16(a, bk, accK, 0, 0, 0);
            }
        }

        if (has_out && t > 0) {
            #pragma unroll
            for (int r = 0; r < 4; ++r) {
                const int row = rbase + quad * 4 + r;
                out[(row * T + (t - 1)) * O + no0 + lm] = accO[r] + bo_v;
            }
        }

        #pragma unroll
        for (int r = 0; r < 4; ++r) {
            const int row = rbase + quad * 4 + r;
            const int col = n0 + lm;
            const float jv = sigmoid_f(accJ[r] + jxr[r]);
            const float kv = sigmoid_f(accK[r] + kxr[r]);
            const float hv = hreg[r];
            const float hn = jv * (1.0f - hv) + (1.0f - kv) * hv;
            hreg[r] = hn;
            hbn[row * H + col] = __float2bfloat16(hn);
        }

        group_post(grp_flags, lblk, t + 1);   // publish h_{t+1}
    }

    group_wait(grp_flags, T);       // h_T published

    // ---- epilogue: out_{T-1} and h_final ----
    {
        const bf16_t* hb = (T & 1) ? hbf1 : hbf0;
        if (has_out) {
            f32x4 accO = {0.f, 0.f, 0.f, 0.f};
            const bf16_t* aP = hb    + (rbase + lm) * H + quad * 8;
            const bf16_t* oP = wo_bf + (no0 + lm) * H + quad * 8;
            #pragma unroll 4
            for (int k0 = 0; k0 < H; k0 += 32) {
                accO = __builtin_amdgcn_mfma_f32_16x16x32_bf16(ldfrag(aP + k0), ldfrag(oP + k0), accO, 0, 0, 0);
            }
            #pragma unroll
            for (int r = 0; r < 4; ++r) {
                const int row = rbase + quad * 4 + r;
                out[(row * T + (T - 1)) * O + no0 + lm] = accO[r] + bo_v;
            }
        }
        const int hfin = B * T * O;
        #pragma unroll
        for (int r = 0; r < 4; ++r) {
            const int row = rbase + quad * 4 + r;
            const int col = n0 + lm;
            out[hfin + row * H + col] = hreg[r];
        }
    }
}

extern "C" void kernel_launch(void* const* d_in, const int* in_sizes, int n_in,
                              void* d_out, int out_size, void* d_ws, size_t ws_size,
                              hipStream_t stream) {
    const float* x   = (const float*)d_in[0];
    const float* h0  = (const float*)d_in[1];
    const float* Wjx = (const float*)d_in[2];
    const float* bjx = (const float*)d_in[3];
    const float* Wjh = (const float*)d_in[4];
    const float* bjh = (const float*)d_in[5];
    const float* Wkx = (const float*)d_in[6];
    const float* bkx = (const float*)d_in[7];
    const float* Wkh = (const float*)d_in[8];
    const float* bkh = (const float*)d_in[9];
    const float* Wo  = (const float*)d_in[10];
    const float* bo  = (const float*)d_in[11];
    const int* seqlen = (const int*)d_in[12];
    float* out = (float*)d_out;

    // workspace layout (bytes)
    char* ws = (char*)d_ws;
    bf16_t* wjh_bf = (bf16_t*)(ws + 0);                 // 2 MB
    bf16_t* wkh_bf = (bf16_t*)(ws + 2097152);           // 2 MB
    bf16_t* wo_bf  = (bf16_t*)(ws + 4194304);           // 1 MB
    bf16_t* wjx_bf = (bf16_t*)(ws + 5242880);           // 1 MB
    bf16_t* wkx_bf = (bf16_t*)(ws + 6291456);           // 1 MB
    bf16_t* x_bf   = (bf16_t*)(ws + 7340032);           // 0.5 MB
    bf16_t* hbf0   = (bf16_t*)(ws + 7864320);           // 1 MB
    bf16_t* hbf1   = (bf16_t*)(ws + 8912896);           // 1 MB
    int*    cnt    = (int*)   (ws + 9961472);           // 8 KB barrier flags

    void* args[] = {
        &x, &h0, &Wjx, &bjx, &Wjh, &bjh, &Wkx, &bkx, &Wkh, &bkh, &Wo, &bo,
        &seqlen, &out,
        &wjh_bf, &wkh_bf, &wo_bf, &wjx_bf, &wkx_bf, &x_bf, &hbf0, &hbf1, &cnt
    };
    hipLaunchCooperativeKernel((const void*)flipflop_rnn_kernel,
                               dim3(512), dim3(256), args, 0, stream);
}

// Round 3
// 2151.571 us; speedup vs baseline: 1.2742x; 1.2742x over previous
//
#include <hip/hip_runtime.h>
#include <hip/hip_bf16.h>
#include <hip/hip_cooperative_groups.h>

namespace cg = cooperative_groups;

constexpr int B = 512;
constexpr int I = 512;
constexpr int H = 1024;
constexpr int O = 512;

using short8 = __attribute__((ext_vector_type(8))) short;
using f32x4  = __attribute__((ext_vector_type(4))) float;
using bf16_t = __hip_bfloat16;

__device__ __forceinline__ short8 ldfrag(const bf16_t* p) {
    return *reinterpret_cast<const short8*>(p);
}
__device__ __forceinline__ float sigmoid_f(float z) {
    return 1.0f / (1.0f + __expf(-z));
}

// ---- RMW-free group barrier, agent-scope flags (compiler-emitted ops) ----
// Group = 64 WGs with the same (blockIdx % 8) = one XCD; h exchange goes
// through the shared XCD L2 (proven correct across two passing rounds:
// plain stores + L1-only invalidate).
// Round-0 barrier pathology: producers fetch_add'ed cnt[t+1] while consumers
// polled cnt[t] -- 4B apart, SAME MALL line -> ~350 serialized line-ops/step
// at the LLC (~11us/step). Round-2 pathology: hand-rolled sc0 asm polls never
// saw the sc0-stored local flags (cache-op semantics wrong) -> the every-64th
// -iteration fallback carried the barrier (+6us/step detection latency).
// This version: monotonic per-WG flags, 16B-spaced (group spans 16 lines, not
// 1), posted with __hip_atomic_store(AGENT) and polled with
// __hip_atomic_load(AGENT) -- the exact load encoding that worked in round 0.
// No RMWs, no resets, one wave polls all 64 flags in parallel (one vector
// load per iteration). h stores are drained to L2 by the __syncthreads
// (implicit vmcnt 0) in group_post BEFORE the flag store; consumers
// buffer_inv sc0 (L1-only) after detection, then read h from the shared L2.
__device__ __forceinline__ void group_wait(const int* flags, int target) {
    if (threadIdx.x < 64) {
        const int* p = flags + threadIdx.x * 4;      // 16B-spaced slots
        while (__hip_atomic_load(p, __ATOMIC_RELAXED, __HIP_MEMORY_SCOPE_AGENT) < target)
            __builtin_amdgcn_s_sleep(1);
    }
    __syncthreads();
    asm volatile("buffer_inv sc0" ::: "memory");     // L1-only invalidate
}

__device__ __forceinline__ void group_post(int* flags, int lblk, int value) {
    __syncthreads();  // drains this WG's h stores to local L2 (vmcnt 0)
    if (threadIdx.x == 0)
        __hip_atomic_store(flags + lblk * 4, value,
                           __ATOMIC_RELAXED, __HIP_MEMORY_SCOPE_AGENT);
}

// 512 WGs x 256 thr, 64KB LDS (Wjh+Wkh slices), 2 WGs/CU.
// WG(g): iblk = g&7 (64 batch rows, XCD-local group), lblk = g>>3 (16 gate cols).
// lblk<32 WGs additionally compute 16 out cols (Wo streamed from L2).
__global__ __launch_bounds__(256, 2)
void flipflop_rnn_kernel(const float* __restrict__ x,  const float* __restrict__ h0,
                         const float* __restrict__ Wjx, const float* __restrict__ bjx,
                         const float* __restrict__ Wjh, const float* __restrict__ bjh,
                         const float* __restrict__ Wkx, const float* __restrict__ bkx,
                         const float* __restrict__ Wkh, const float* __restrict__ bkh,
                         const float* __restrict__ Wo,  const float* __restrict__ bo,
                         const int* __restrict__ seqlen,
                         float* __restrict__ out,
                         bf16_t* __restrict__ wjh_bf, bf16_t* __restrict__ wkh_bf,
                         bf16_t* __restrict__ wo_bf,  bf16_t* __restrict__ wjx_bf,
                         bf16_t* __restrict__ wkx_bf, bf16_t* __restrict__ x_bf,
                         bf16_t* __restrict__ hbf0,   bf16_t* __restrict__ hbf1,
                         int* __restrict__ cnt)
{
    // [gate][kb 0..127][col 0..15][8 shorts] = 65536 B
    __shared__ short lds_w[32768];

    const int T    = seqlen[0];
    const int tid  = threadIdx.x;
    const int g    = blockIdx.x;
    const int nthr = gridDim.x * blockDim.x;
    const int gtid = g * blockDim.x + tid;

    // ---- cast weights & x to bf16; zero barrier flags ----
    for (int idx = gtid; idx < H * H; idx += nthr) wjh_bf[idx] = __float2bfloat16(Wjh[idx]);
    for (int idx = gtid; idx < H * H; idx += nthr) wkh_bf[idx] = __float2bfloat16(Wkh[idx]);
    for (int idx = gtid; idx < O * H; idx += nthr) wo_bf[idx]  = __float2bfloat16(Wo[idx]);
    for (int idx = gtid; idx < H * I; idx += nthr) wjx_bf[idx] = __float2bfloat16(Wjx[idx]);
    for (int idx = gtid; idx < H * I; idx += nthr) wkx_bf[idx] = __float2bfloat16(Wkx[idx]);
    for (int idx = gtid; idx < B * I; idx += nthr) x_bf[idx]   = __float2bfloat16(x[idx]);
    if (gtid < 8 * 256) cnt[gtid] = 0;   // 8 groups x 64 flags x 16B spacing

    // ---- geometry ----
    const int w     = tid >> 6;
    const int lane  = tid & 63;
    const int quad  = lane >> 4;
    const int lm    = lane & 15;
    const int iblk  = g & 7;            // XCD-local group id
    const int lblk  = g >> 3;           // 0..63
    const int rbase = iblk * 64 + w * 16;
    const int n0    = lblk * 16;        // gate cols
    const bool has_out = (lblk < 32);
    const int no0   = lblk * 16;        // out cols (valid when has_out)
    int* grp_flags = cnt + iblk * 256;  // this group's 64 flags (16B-spaced)

    // ---- h0 init: each thread owns 4 (row,col) elements ----
    float hreg[4];
    #pragma unroll
    for (int r = 0; r < 4; ++r) {
        const int row = rbase + quad * 4 + r;
        const int col = n0 + lm;
        const float hv = h0[row * H + col];
        hreg[r] = hv;
        hbf0[row * H + col] = __float2bfloat16(hv);
    }

    cg::this_grid().sync();   // casts + h0 + flag zeros visible device-wide

    // ---- load this WG's Wjh/Wkh rows into LDS (one time) ----
    for (int c = tid; c < 4096; c += 256) {
        const int gate = c >> 11;
        const int cc   = c & 2047;
        const int kb   = cc >> 4;
        const int col  = cc & 15;
        const bf16_t* src = (gate ? wkh_bf : wjh_bf) + (n0 + col) * H + kb * 8;
        *reinterpret_cast<short8*>(&lds_w[c * 8]) = *reinterpret_cast<const short8*>(src);
    }
    __syncthreads();

    // ---- jx/kx (+ all biases) in registers ----
    float jxr[4], kxr[4];
    {
        f32x4 aJ = {0.f, 0.f, 0.f, 0.f};
        f32x4 aK = {0.f, 0.f, 0.f, 0.f};
        const bf16_t* aP = x_bf   + (rbase + lm) * I + quad * 8;
        const bf16_t* jP = wjx_bf + (n0 + lm) * I + quad * 8;
        const bf16_t* kP = wkx_bf + (n0 + lm) * I + quad * 8;
        #pragma unroll 4
        for (int k0 = 0; k0 < I; k0 += 32) {
            short8 a = ldfrag(aP + k0);
            aJ = __builtin_amdgcn_mfma_f32_16x16x32_bf16(a, ldfrag(jP + k0), aJ, 0, 0, 0);
            aK = __builtin_amdgcn_mfma_f32_16x16x32_bf16(a, ldfrag(kP + k0), aK, 0, 0, 0);
        }
        const int col = n0 + lm;
        #pragma unroll
        for (int r = 0; r < 4; ++r) {
            jxr[r] = aJ[r] + bjx[col] + bjh[col];
            kxr[r] = aK[r] + bkx[col] + bkh[col];
        }
    }
    const float bo_v = has_out ? bo[no0 + lm] : 0.0f;

    // ---- recurrence: step t reads h_t, computes h_{t+1} and out_{t-1} ----
    for (int t = 0; t < T; ++t) {
        if (t > 0) group_wait(grp_flags, t);   // h_t published by all 64 group WGs
        const bf16_t* hb  = (t & 1) ? hbf1 : hbf0;
        bf16_t*       hbn = (t & 1) ? hbf0 : hbf1;

        f32x4 accJ = {0.f, 0.f, 0.f, 0.f};
        f32x4 accK = {0.f, 0.f, 0.f, 0.f};
        f32x4 accO = {0.f, 0.f, 0.f, 0.f};

        const bf16_t* aP = hb    + (rbase + lm) * H + quad * 8;
        const bf16_t* oP = wo_bf + (no0 + lm) * H + quad * 8;
        const short*  jL = lds_w + quad * 128 + lm * 8;          // [kb][col][8]
        const short*  kL = jL + 16384;

        if (has_out) {
            #pragma unroll 4
            for (int k0 = 0; k0 < H; k0 += 32) {
                short8 a  = ldfrag(aP + k0);
                short8 bj = *reinterpret_cast<const short8*>(jL + (k0 >> 3) * 128);
                short8 bk = *reinterpret_cast<const short8*>(kL + (k0 >> 3) * 128);
                accJ = __builtin_amdgcn_mfma_f32_16x16x32_bf16(a, bj, accJ, 0, 0, 0);
                accK = __builtin_amdgcn_mfma_f32_16x16x32_bf16(a, bk, accK, 0, 0, 0);
                accO = __builtin_amdgcn_mfma_f32_16x16x32_bf16(a, ldfrag(oP + k0), accO, 0, 0, 0);
            }
        } else {
            #pragma unroll 4
            for (int k0 = 0; k0 < H; k0 += 32) {
                short8 a  = ldfrag(aP + k0);
                short8 bj = *reinterpret_cast<const short8*>(jL + (k0 >> 3) * 128);
                short8 bk = *reinterpret_cast<const short8*>(kL + (k0 >> 3) * 128);
                accJ = __builtin_amdgcn_mfma_f32_16x16x32_bf16(a, bj, accJ, 0, 0, 0);
                accK = __builtin_amdgcn_mfma_f32_16x16x32_bf16(a, bk, accK, 0, 0, 0);
            }
        }

        // h update + publish FIRST (critical path for the whole group) ...
        #pragma unroll
        for (int r = 0; r < 4; ++r) {
            const int row = rbase + quad * 4 + r;
            const int col = n0 + lm;
            const float jv = sigmoid_f(accJ[r] + jxr[r]);
            const float kv = sigmoid_f(accK[r] + kxr[r]);
            const float hv = hreg[r];
            const float hn = jv * (1.0f - hv) + (1.0f - kv) * hv;
            hreg[r] = hn;
            hbn[row * H + col] = __float2bfloat16(hn);
        }

        group_post(grp_flags, lblk, t + 1);   // publish h_{t+1}

        // ... THEN the fire-and-forget out stores (accO lives in registers;
        // off the post's vmcnt-drain critical path, drains during next wait).
        if (has_out && t > 0) {
            #pragma unroll
            for (int r = 0; r < 4; ++r) {
                const int row = rbase + quad * 4 + r;
                out[(row * T + (t - 1)) * O + no0 + lm] = accO[r] + bo_v;
            }
        }
    }

    group_wait(grp_flags, T);       // h_T published

    // ---- epilogue: out_{T-1} and h_final ----
    {
        const bf16_t* hb = (T & 1) ? hbf1 : hbf0;
        if (has_out) {
            f32x4 accO = {0.f, 0.f, 0.f, 0.f};
            const bf16_t* aP = hb    + (rbase + lm) * H + quad * 8;
            const bf16_t* oP = wo_bf + (no0 + lm) * H + quad * 8;
            #pragma unroll 4
            for (int k0 = 0; k0 < H; k0 += 32) {
                accO = __builtin_amdgcn_mfma_f32_16x16x32_bf16(ldfrag(aP + k0), ldfrag(oP + k0), accO, 0, 0, 0);
            }
            #pragma unroll
            for (int r = 0; r < 4; ++r) {
                const int row = rbase + quad * 4 + r;
                out[(row * T + (T - 1)) * O + no0 + lm] = accO[r] + bo_v;
            }
        }
        const int hfin = B * T * O;
        #pragma unroll
        for (int r = 0; r < 4; ++r) {
            const int row = rbase + quad * 4 + r;
            const int col = n0 + lm;
            out[hfin + row * H + col] = hreg[r];
        }
    }
}

extern "C" void kernel_launch(void* const* d_in, const int* in_sizes, int n_in,
                              void* d_out, int out_size, void* d_ws, size_t ws_size,
                              hipStream_t stream) {
    const float* x   = (const float*)d_in[0];
    const float* h0  = (const float*)d_in[1];
    const float* Wjx = (const float*)d_in[2];
    const float* bjx = (const float*)d_in[3];
    const float* Wjh = (const float*)d_in[4];
    const float* bjh = (const float*)d_in[5];
    const float* Wkx = (const float*)d_in[6];
    const float* bkx = (const float*)d_in[7];
    const float* Wkh = (const float*)d_in[8];
    const float* bkh = (const float*)d_in[9];
    const float* Wo  = (const float*)d_in[10];
    const float* bo  = (const float*)d_in[11];
    const int* seqlen = (const int*)d_in[12];
    float* out = (float*)d_out;

    // workspace layout (bytes)
    char* ws = (char*)d_ws;
    bf16_t* wjh_bf = (bf16_t*)(ws + 0);                 // 2 MB
    bf16_t* wkh_bf = (bf16_t*)(ws + 2097152);           // 2 MB
    bf16_t* wo_bf  = (bf16_t*)(ws + 4194304);           // 1 MB
    bf16_t* wjx_bf = (bf16_t*)(ws + 5242880);           // 1 MB
    bf16_t* wkx_bf = (bf16_t*)(ws + 6291456);           // 1 MB
    bf16_t* x_bf   = (bf16_t*)(ws + 7340032);           // 0.5 MB
    bf16_t* hbf0   = (bf16_t*)(ws + 7864320);           // 1 MB
    bf16_t* hbf1   = (bf16_t*)(ws + 8912896);           // 1 MB
    int*    cnt    = (int*)   (ws + 9961472);           // 8 KB barrier flags

    void* args[] = {
        &x, &h0, &Wjx, &bjx, &Wjh, &bjh, &Wkx, &bkx, &Wkh, &bkh, &Wo, &bo,
        &seqlen, &out,
        &wjh_bf, &wkh_bf, &wo_bf, &wjx_bf, &wkx_bf, &x_bf, &hbf0, &hbf1, &cnt
    };
    hipLaunchCooperativeKernel((const void*)flipflop_rnn_kernel,
                               dim3(512), dim3(256), args, 0, stream);
}